// Round 11
// baseline (253.748 us; speedup 1.0000x reference)
//
#include <hip/hip_runtime.h>
#include <hip/hip_bf16.h>

#define EMBED 768
#define HEADS 12
#define TOKENS 32768          // B*S = 32*1024
#define QKVN  (3*EMBED)       // 2304
#define KDIM  768
#define NKT   (KDIM/64)       // 12 K-tiles of 64
#define QK_SCALE 0.03608439182435161f  // 768^-0.5

typedef __attribute__((ext_vector_type(8))) __bf16 bf16x8;
typedef __attribute__((ext_vector_type(4))) __bf16 bf16x4;
typedef __attribute__((ext_vector_type(4))) float  f32x4;

__device__ __forceinline__ void gload_lds16(const void* gptr, void* lptr) {
    __builtin_amdgcn_global_load_lds(
        (const __attribute__((address_space(1))) void*)gptr,
        (__attribute__((address_space(3))) void*)lptr,
        16, 0, 0);
}

// ---------------- f32 -> bf16 cast (vectorized) ----------------
__global__ __launch_bounds__(256) void k_cvt_bf16(const float4* __restrict__ src,
                                                  bf16x4* __restrict__ dst, int n4) {
    int i = blockIdx.x * blockDim.x + threadIdx.x;
    int stride = gridDim.x * blockDim.x;
    for (; i < n4; i += stride) {
        float4 f = src[i];
        bf16x4 o;
        o[0] = (__bf16)f.x; o[1] = (__bf16)f.y; o[2] = (__bf16)f.z; o[3] = (__bf16)f.w;
        dst[i] = o;
    }
}

// -------- pack weights [K][N] f32 -> MFMA-fragment order bf16 --------
// BF[kt][n16][ks][lane][8]: lane l holds col n16*16+(l&15), k = kt*64+ks*32+(l>>4)*8+e.
// A wave's B-frag load is then ONE fully-coalesced global_load_dwordx4.
__global__ __launch_bounds__(256) void k_pack_b(const float* __restrict__ w,
                                                __bf16* __restrict__ BF, int N) {
    int tid = blockIdx.x * 256 + threadIdx.x;
    int lane = tid & 63;
    int rest = tid >> 6;
    int N16 = N >> 4;
    int ks = rest & 1;
    int n16 = (rest >> 1) % N16;
    int kt = (rest >> 1) / N16;
    if (kt >= NKT) return;
    int col = n16 * 16 + (lane & 15);
    int k0 = kt * 64 + ks * 32 + (lane >> 4) * 8;
    bf16x8 o;
#pragma unroll
    for (int e = 0; e < 8; ++e) o[e] = (__bf16)w[(size_t)(k0 + e) * N + col];
    *(bf16x8*)(BF + (size_t)tid * 8) = o;
}

// ======== 64x256 bf16 MFMA GEMM, BK=64, B direct from L2, 3 blocks/CU ========
// Shrunk from 128x256 (R6/R8): acc 64 VGPR -> total ~150 fits the (256,3)
// allocator cap (~170), unlike the 128-acc version (R9: clamped to 84, 10x
// spill).  A-only LDS ring-3 (3 x 8KB = 24KB; 3 blocks = 72KB <= 160KB),
// XOR-swizzled (chunk ^= row&7).  Per K-step: 8 ds_read(A-frags), 16 MFMA,
// load bfv[0..3](t+1), 16 MFMA, load bfv[4..7], 2 gload_lds A(t+2),
// vmcnt(10) [keeps this step's 10 issues, drains stageA(t+1)], ONE barrier.
// bfv RAW across steps enforced by compiler-inserted vmcnt on reg use.
template <typename OutT>
__global__ __launch_bounds__(256, 3) void gemm_bl(const __bf16* __restrict__ A,
                                                  const __bf16* __restrict__ BF,
                                                  const float* __restrict__ bias,
                                                  OutT* __restrict__ C, int N) {
    __shared__ __align__(1024) char lds[24576];
    const int tid = threadIdx.x;
    const int w = tid >> 6, lane = tid & 63;
    const int l15 = lane & 15, l16 = lane >> 4;
    const int K = KDIM;
    const int N16 = N >> 4;
    const long ktstride = (long)N16 * 1024;   // elems per kt in BF

    // XCD-aware block swizzle (grid % 8 == 0 for both our grids)
    const int nbx = N >> 8;
    const int cpx = gridDim.x >> 3;
    const int bid = blockIdx.x;
    const int swz = (bid & 7) * cpx + (bid >> 3);
    const int brow = swz / nbx, bcol = swz % nbx;
    const long arow0 = (long)brow * 64;
    const int  ncol0 = bcol * 256;

    // ---- A staging: linear LDS dest, pre-swizzled global source ----
    // dest o = slot*8192 + j*4096 + w*1024 + lane*16 -> row = j*32+w*8+(lane>>3),
    // chunk' = lane&7; source chunk = chunk' ^ (row&7) = (lane&7)^(lane>>3).
    const __bf16* Asrc = A + (arow0 + w * 8 + (lane >> 3)) * K
                           + (((lane & 7) ^ (lane >> 3)) * 8);
    auto stageA = [&](int slot, int kt) {
#pragma unroll
        for (int j = 0; j < 2; ++j)
            gload_lds16(Asrc + (long)(j * 32) * K + (long)kt * 64,
                        lds + slot * 8192 + j * 4096 + w * 1024 + lane * 16);
    };

    // ---- A-frag read offsets (swizzled): row = mf*16+l15, chunk=(ks*4+l16)^(l15&7)
    const int cA0 = l15 * 128 + (((0 * 4 + l16) ^ (l15 & 7)) * 16);
    const int cA1 = l15 * 128 + (((1 * 4 + l16) ^ (l15 & 7)) * 16);

    // ---- B fragment base: wave w covers n16 = (ncol0>>4) + w*4 + n ----
    const __bf16* bbase = BF + (size_t)lane * 8 + ((long)(ncol0 >> 4) + w * 4) * 1024;

    f32x4 acc[4][4] = {};
    bf16x8 bfv[8];

#define LOADB(KT, HALF) do { \
    _Pragma("unroll") for (int n = 0; n < 4; ++n) \
        bfv[(HALF) * 4 + n] = *(const bf16x8*)(bbase + (long)(KT) * ktstride + n * 1024 + (HALF) * 512); \
} while (0)

#define VMW10 asm volatile("s_waitcnt vmcnt(10)" ::: "memory")
#define VMW8  asm volatile("s_waitcnt vmcnt(8)"  ::: "memory")

#define KSTEP(SLOT, BKT, AKT, VMW, DOBAR) do { \
    bf16x8 af[8]; \
    _Pragma("unroll") for (int mf = 0; mf < 4; ++mf) \
        af[mf] = *(const bf16x8*)(lds + (SLOT) * 8192 + mf * 2048 + cA0); \
    _Pragma("unroll") for (int mf = 0; mf < 4; ++mf) \
        af[4 + mf] = *(const bf16x8*)(lds + (SLOT) * 8192 + mf * 2048 + cA1); \
    __builtin_amdgcn_s_setprio(1); \
    _Pragma("unroll") for (int mf = 0; mf < 4; ++mf) \
        _Pragma("unroll") for (int n = 0; n < 4; ++n) \
            acc[mf][n] = __builtin_amdgcn_mfma_f32_16x16x32_bf16(af[mf], bfv[n], acc[mf][n], 0, 0, 0); \
    __builtin_amdgcn_s_setprio(0); \
    if ((BKT) >= 0) LOADB(BKT, 0); \
    __builtin_amdgcn_s_setprio(1); \
    _Pragma("unroll") for (int mf = 0; mf < 4; ++mf) \
        _Pragma("unroll") for (int n = 0; n < 4; ++n) \
            acc[mf][n] = __builtin_amdgcn_mfma_f32_16x16x32_bf16(af[4 + mf], bfv[4 + n], acc[mf][n], 0, 0, 0); \
    __builtin_amdgcn_s_setprio(0); \
    if ((BKT) >= 0) LOADB(BKT, 1); \
    if ((AKT) >= 0) stageA((AKT) % 3, (AKT)); \
    VMW; \
    if (DOBAR) { __builtin_amdgcn_s_barrier(); __builtin_amdgcn_sched_barrier(0); } \
} while (0)

    // ---- prologue: A(0), B(0), drain, A(1) in flight ----
    stageA(0, 0);
    LOADB(0, 0); LOADB(0, 1);
    asm volatile("s_waitcnt vmcnt(0)" ::: "memory");
    stageA(1, 1);
    __builtin_amdgcn_s_barrier();
    __builtin_amdgcn_sched_barrier(0);

    // ---- main: t=0..8 (3x3), then peel 9,10,11 ----
    for (int t = 0; t < 9; t += 3) {
        KSTEP(0, t + 1, t + 2, VMW10, 1);
        KSTEP(1, t + 2, t + 3, VMW10, 1);
        KSTEP(2, t + 3, t + 4, VMW10, 1);
    }
    KSTEP(0, 10, 11, VMW10, 1);
    KSTEP(1, 11, -1, VMW8, 1);
    KSTEP(2, -1, -1, , 0);
#undef KSTEP
#undef LOADB
#undef VMW10
#undef VMW8

    // ---- C write: row = arow0 + mf*16 + l16*4 + j, col = ncol0 + w*64 + n*16 + l15
#pragma unroll
    for (int mf = 0; mf < 4; ++mf) {
        const int row = (int)arow0 + mf * 16 + l16 * 4;
#pragma unroll
        for (int n = 0; n < 4; ++n) {
            const int col = ncol0 + w * 64 + n * 16 + l15;
            const float bv = bias[col];
#pragma unroll
            for (int j = 0; j < 4; ++j) {
                C[(long)(row + j) * N + col] = (OutT)(acc[mf][n][j] + bv);
            }
        }
    }
}

// ---------------- per-token 12x12 head attention ----------------
#define HPITCH 200
__global__ __launch_bounds__(256) void k_attn(const __bf16* __restrict__ qkv,
                                              __bf16* __restrict__ out) {
    __shared__ __bf16 rows[4][12 * HPITCH];
    __shared__ float wts[4][144];
    const int w = threadIdx.x >> 6, lane = threadIdx.x & 63;
    const long token = (long)blockIdx.x * 4 + w;
    const __bf16* rp = qkv + token * QKVN;
    __bf16* row = rows[w];
    float* wt  = wts[w];

#pragma unroll
    for (int i = 0; i < 4; i++) {
        int c = i * 64 + lane;
        int h = c / 24;
        *(bf16x8*)(row + h * HPITCH + (c * 8 - h * 192)) = *(const bf16x8*)(rp + c * 8);
    }
    if (lane < 32) {
        int c = 256 + lane;
        int h = c / 24;
        *(bf16x8*)(row + h * HPITCH + (c * 8 - h * 192)) = *(const bf16x8*)(rp + c * 8);
    }
    __syncthreads();

    for (int p = lane; p < 144; p += 64) {
        int h = p / 12, g = p - h * 12;
        const __bf16* qp = row + h * HPITCH;
        const __bf16* kp = row + g * HPITCH + 64;
        float s = 0.f;
#pragma unroll
        for (int d = 0; d < 64; d += 8) {
            bf16x8 qv = *(const bf16x8*)(qp + d);
            bf16x8 kv = *(const bf16x8*)(kp + d);
#pragma unroll
            for (int j = 0; j < 8; j++) s += (float)qv[j] * (float)kv[j];
        }
        wt[p] = s * QK_SCALE;
    }
    __syncthreads();

    if (lane < 12) {
        float s[12];
#pragma unroll
        for (int g = 0; g < 12; g++) s[g] = wt[lane * 12 + g];
        float m = s[0];
#pragma unroll
        for (int g = 1; g < 12; g++) m = fmaxf(m, s[g]);
        float sum = 0.f;
#pragma unroll
        for (int g = 0; g < 12; g++) { s[g] = __expf(s[g] - m); sum += s[g]; }
        float inv = 1.0f / sum;
#pragma unroll
        for (int g = 0; g < 12; g++) wt[lane * 12 + g] = s[g] * inv;
    }
    __syncthreads();

    float vr[12];
#pragma unroll
    for (int g = 0; g < 12; g++) vr[g] = (float)row[g * HPITCH + 128 + lane];
#pragma unroll
    for (int h = 0; h < 12; h++) {
        float a = 0.f;
#pragma unroll
        for (int g = 0; g < 12; g++) a += wt[h * 12 + g] * vr[g];
        out[token * EMBED + h * 64 + lane] = (__bf16)a;
    }
}

extern "C" void kernel_launch(void* const* d_in, const int* in_sizes, int n_in,
                              void* d_out, int out_size, void* d_ws, size_t ws_size,
                              hipStream_t stream) {
    const float* x     = (const float*)d_in[0];
    const float* w_qkv = (const float*)d_in[1];
    const float* b_qkv = (const float*)d_in[2];
    const float* w_o   = (const float*)d_in[3];
    const float* b_o   = (const float*)d_in[4];
    float* out = (float*)d_out;

    char* ws = (char*)d_ws;
    size_t off = 0;
    auto take = [&](size_t bytes) {
        char* p = ws + off;
        off += (bytes + 255) & ~(size_t)255;
        return p;
    };
    __bf16* wqkvp = (__bf16*)take((size_t)QKVN * KDIM * 2);   // packed B for GEMM1
    __bf16* wop   = (__bf16*)take((size_t)EMBED * KDIM * 2);  // packed B for GEMM2
    __bf16* xb    = (__bf16*)take((size_t)TOKENS * EMBED * 2);
    __bf16* qkvb  = (__bf16*)take((size_t)TOKENS * QKVN * 2);
    __bf16* attno = xb;  // x_bf16 dead after GEMM1; reuse

    int n4 = TOKENS * EMBED / 4;
    k_cvt_bf16<<<2048, 256, 0, stream>>>((const float4*)x, (bf16x4*)xb, n4);

    // pack weights into fragment order
    k_pack_b<<<(NKT * (QKVN / 16) * 2 * 64) / 256, 256, 0, stream>>>(w_qkv, wqkvp, QKVN);
    k_pack_b<<<(NKT * (EMBED / 16) * 2 * 64) / 256, 256, 0, stream>>>(w_o, wop, EMBED);

    // GEMM1: qkv = x @ w_qkv + b_qkv -> bf16   (4608 wg, %8==0)
    gemm_bl<__bf16><<<(TOKENS / 64) * (QKVN / 256), 256, 0, stream>>>(
        xb, wqkvp, b_qkv, qkvb, QKVN);

    k_attn<<<TOKENS / 4, 256, 0, stream>>>(qkvb, attno);

    // GEMM2: out = attn_out @ w_o + b_o -> f32  (1536 wg, %8==0)
    gemm_bl<float><<<(TOKENS / 64) * (EMBED / 256), 256, 0, stream>>>(
        attno, wop, b_o, out, EMBED);
}

// Round 12
// 235.985 us; speedup vs baseline: 1.0753x; 1.0753x over previous
//
#include <hip/hip_runtime.h>
#include <hip/hip_bf16.h>

#define EMBED 768
#define HEADS 12
#define TOKENS 32768          // B*S = 32*1024
#define QKVN  (3*EMBED)       // 2304
#define KDIM  768
#define NKT   (KDIM/64)       // 12 K-tiles of 64
#define QK_SCALE 0.03608439182435161f  // 768^-0.5

typedef __attribute__((ext_vector_type(8))) __bf16 bf16x8;
typedef __attribute__((ext_vector_type(4))) __bf16 bf16x4;
typedef __attribute__((ext_vector_type(4))) float  f32x4;

__device__ __forceinline__ void gload_lds16(const void* gptr, void* lptr) {
    __builtin_amdgcn_global_load_lds(
        (const __attribute__((address_space(1))) void*)gptr,
        (__attribute__((address_space(3))) void*)lptr,
        16, 0, 0);
}

// ---------------- f32 -> bf16 cast (vectorized) ----------------
__global__ __launch_bounds__(256) void k_cvt_bf16(const float4* __restrict__ src,
                                                  bf16x4* __restrict__ dst, int n4) {
    int i = blockIdx.x * blockDim.x + threadIdx.x;
    int stride = gridDim.x * blockDim.x;
    for (; i < n4; i += stride) {
        float4 f = src[i];
        bf16x4 o;
        o[0] = (__bf16)f.x; o[1] = (__bf16)f.y; o[2] = (__bf16)f.z; o[3] = (__bf16)f.w;
        dst[i] = o;
    }
}

// -------- pack weights [K][N] f32 -> MFMA-fragment order bf16 --------
// BF[kt][n16][ks][lane][8]: lane l holds col n16*16+(l&15), k = kt*64+ks*32+(l>>4)*8+e.
// A wave's B-frag load is then ONE fully-coalesced global_load_dwordx4.
__global__ __launch_bounds__(256) void k_pack_b(const float* __restrict__ w,
                                                __bf16* __restrict__ BF, int N) {
    int tid = blockIdx.x * 256 + threadIdx.x;
    int lane = tid & 63;
    int rest = tid >> 6;
    int N16 = N >> 4;
    int ks = rest & 1;
    int n16 = (rest >> 1) % N16;
    int kt = (rest >> 1) / N16;
    if (kt >= NKT) return;
    int col = n16 * 16 + (lane & 15);
    int k0 = kt * 64 + ks * 32 + (lane >> 4) * 8;
    bf16x8 o;
#pragma unroll
    for (int e = 0; e < 8; ++e) o[e] = (__bf16)w[(size_t)(k0 + e) * N + col];
    *(bf16x8*)(BF + (size_t)tid * 8) = o;
}

// ======== 128x256 bf16 MFMA GEMM, BK=64, B direct from L2 (no B-LDS) ========
// A-only LDS ring-3 (48KB), XOR-swizzled (chunk ^= row&7).  Per K-step:
// 16 ds_read(A-frags), 32 MFMA, load bfv[0..3](t+1), 32 MFMA, load bfv[4..7],
// 4 gload_lds A(t+2), vmcnt(12) [drains A(t+1) only], ONE barrier.
// Ledger: queue at VMW12 = [bfv1(t),stageA(t+1) | bfv0(t+1),bfv1(t+1),stageA(t+2)]
// -> drains through stageA(t+1) (ring-3 gives it a 2-step landing window).
// Occupancy ledger (do not revisit): (256,2)@128VGPR = best;
// (256,3)@BM128 -> VGPR clamp 84, acc spills, 10x regress (R9);
// (256,3)@BM64  -> VGPR clamp 76, bfv spills, -12% (R11).
template <typename OutT>
__global__ __launch_bounds__(256, 2) void gemm_bl(const __bf16* __restrict__ A,
                                                  const __bf16* __restrict__ BF,
                                                  const float* __restrict__ bias,
                                                  OutT* __restrict__ C, int N) {
    __shared__ __align__(1024) char lds[49152];
    const int tid = threadIdx.x;
    const int w = tid >> 6, lane = tid & 63;
    const int l15 = lane & 15, l16 = lane >> 4;
    const int K = KDIM;
    const int N16 = N >> 4;
    const long ktstride = (long)N16 * 1024;   // elems per kt in BF

    // XCD-aware block swizzle (grid % 8 == 0 for both our grids)
    const int nbx = N >> 8;
    const int cpx = gridDim.x >> 3;
    const int bid = blockIdx.x;
    const int swz = (bid & 7) * cpx + (bid >> 3);
    const int brow = swz / nbx, bcol = swz % nbx;
    const long arow0 = (long)brow * 128;
    const int  ncol0 = bcol * 256;

    // ---- A staging: linear LDS dest, pre-swizzled global source ----
    // dest o = slot*16K + j*4096 + w*1024 + lane*16 -> row = j*32+w*8+(lane>>3),
    // chunk' = lane&7; source chunk = chunk' ^ (row&7) = (lane&7)^(lane>>3).
    const __bf16* Asrc = A + (arow0 + w * 8 + (lane >> 3)) * K
                           + (((lane & 7) ^ (lane >> 3)) * 8);
    auto stageA = [&](int slot, int kt) {
#pragma unroll
        for (int j = 0; j < 4; ++j)
            gload_lds16(Asrc + (long)(j * 32) * K + (long)kt * 64,
                        lds + slot * 16384 + j * 4096 + w * 1024 + lane * 16);
    };

    // ---- A-frag read offsets (swizzled): row = mf*16+l15, chunk=(ks*4+l16)^(l15&7)
    const int cA0 = l15 * 128 + (((0 * 4 + l16) ^ (l15 & 7)) * 16);
    const int cA1 = l15 * 128 + (((1 * 4 + l16) ^ (l15 & 7)) * 16);

    // ---- B fragment base: wave w covers n16 = (ncol0>>4) + w*4 + n ----
    const __bf16* bbase = BF + (size_t)lane * 8 + ((long)(ncol0 >> 4) + w * 4) * 1024;

    f32x4 acc[8][4] = {};
    bf16x8 bfv[8];

#define LOADB(KT, HALF) do { \
    _Pragma("unroll") for (int n = 0; n < 4; ++n) \
        bfv[(HALF) * 4 + n] = *(const bf16x8*)(bbase + (long)(KT) * ktstride + n * 1024 + (HALF) * 512); \
} while (0)

#define VMW12 asm volatile("s_waitcnt vmcnt(12)" ::: "memory")
#define VMW8  asm volatile("s_waitcnt vmcnt(8)"  ::: "memory")

#define KSTEP(SLOT, BKT, AKT, VMW, DOBAR) do { \
    bf16x8 af[16]; \
    _Pragma("unroll") for (int mf = 0; mf < 8; ++mf) \
        af[mf] = *(const bf16x8*)(lds + (SLOT) * 16384 + mf * 2048 + cA0); \
    _Pragma("unroll") for (int mf = 0; mf < 8; ++mf) \
        af[8 + mf] = *(const bf16x8*)(lds + (SLOT) * 16384 + mf * 2048 + cA1); \
    __builtin_amdgcn_s_setprio(1); \
    _Pragma("unroll") for (int mf = 0; mf < 8; ++mf) \
        _Pragma("unroll") for (int n = 0; n < 4; ++n) \
            acc[mf][n] = __builtin_amdgcn_mfma_f32_16x16x32_bf16(af[mf], bfv[n], acc[mf][n], 0, 0, 0); \
    __builtin_amdgcn_s_setprio(0); \
    if ((BKT) >= 0) LOADB(BKT, 0); \
    __builtin_amdgcn_s_setprio(1); \
    _Pragma("unroll") for (int mf = 0; mf < 8; ++mf) \
        _Pragma("unroll") for (int n = 0; n < 4; ++n) \
            acc[mf][n] = __builtin_amdgcn_mfma_f32_16x16x32_bf16(af[8 + mf], bfv[4 + n], acc[mf][n], 0, 0, 0); \
    __builtin_amdgcn_s_setprio(0); \
    if ((BKT) >= 0) LOADB(BKT, 1); \
    if ((AKT) >= 0) stageA((AKT) % 3, (AKT)); \
    VMW; \
    if (DOBAR) { __builtin_amdgcn_s_barrier(); __builtin_amdgcn_sched_barrier(0); } \
} while (0)

    // ---- prologue: A(0), B(0), drain, A(1) in flight ----
    stageA(0, 0);
    LOADB(0, 0); LOADB(0, 1);
    asm volatile("s_waitcnt vmcnt(0)" ::: "memory");
    stageA(1, 1);
    __builtin_amdgcn_s_barrier();
    __builtin_amdgcn_sched_barrier(0);

    // ---- main: t=0..8 (3x3), then peel 9,10,11 ----
    for (int t = 0; t < 9; t += 3) {
        KSTEP(0, t + 1, t + 2, VMW12, 1);
        KSTEP(1, t + 2, t + 3, VMW12, 1);
        KSTEP(2, t + 3, t + 4, VMW12, 1);
    }
    KSTEP(0, 10, 11, VMW12, 1);
    KSTEP(1, 11, -1, VMW8, 1);
    KSTEP(2, -1, -1, , 0);
#undef KSTEP
#undef LOADB
#undef VMW12
#undef VMW8

    // ---- C write: row = arow0 + mf*16 + l16*4 + j, col = ncol0 + w*64 + n*16 + l15
#pragma unroll
    for (int mf = 0; mf < 8; ++mf) {
        const int row = (int)arow0 + mf * 16 + l16 * 4;
#pragma unroll
        for (int n = 0; n < 4; ++n) {
            const int col = ncol0 + w * 64 + n * 16 + l15;
            const float bv = bias[col];
#pragma unroll
            for (int j = 0; j < 4; ++j) {
                C[(long)(row + j) * N + col] = (OutT)(acc[mf][n][j] + bv);
            }
        }
    }
}

// ---------------- per-token 12x12 head attention ----------------
#define HPITCH 200
__global__ __launch_bounds__(256) void k_attn(const __bf16* __restrict__ qkv,
                                              __bf16* __restrict__ out) {
    __shared__ __bf16 rows[4][12 * HPITCH];
    __shared__ float wts[4][144];
    const int w = threadIdx.x >> 6, lane = threadIdx.x & 63;
    const long token = (long)blockIdx.x * 4 + w;
    const __bf16* rp = qkv + token * QKVN;
    __bf16* row = rows[w];
    float* wt  = wts[w];

#pragma unroll
    for (int i = 0; i < 4; i++) {
        int c = i * 64 + lane;
        int h = c / 24;
        *(bf16x8*)(row + h * HPITCH + (c * 8 - h * 192)) = *(const bf16x8*)(rp + c * 8);
    }
    if (lane < 32) {
        int c = 256 + lane;
        int h = c / 24;
        *(bf16x8*)(row + h * HPITCH + (c * 8 - h * 192)) = *(const bf16x8*)(rp + c * 8);
    }
    __syncthreads();

    for (int p = lane; p < 144; p += 64) {
        int h = p / 12, g = p - h * 12;
        const __bf16* qp = row + h * HPITCH;
        const __bf16* kp = row + g * HPITCH + 64;
        float s = 0.f;
#pragma unroll
        for (int d = 0; d < 64; d += 8) {
            bf16x8 qv = *(const bf16x8*)(qp + d);
            bf16x8 kv = *(const bf16x8*)(kp + d);
#pragma unroll
            for (int j = 0; j < 8; j++) s += (float)qv[j] * (float)kv[j];
        }
        wt[p] = s * QK_SCALE;
    }
    __syncthreads();

    if (lane < 12) {
        float s[12];
#pragma unroll
        for (int g = 0; g < 12; g++) s[g] = wt[lane * 12 + g];
        float m = s[0];
#pragma unroll
        for (int g = 1; g < 12; g++) m = fmaxf(m, s[g]);
        float sum = 0.f;
#pragma unroll
        for (int g = 0; g < 12; g++) { s[g] = __expf(s[g] - m); sum += s[g]; }
        float inv = 1.0f / sum;
#pragma unroll
        for (int g = 0; g < 12; g++) wt[lane * 12 + g] = s[g] * inv;
    }
    __syncthreads();

    float vr[12];
#pragma unroll
    for (int g = 0; g < 12; g++) vr[g] = (float)row[g * HPITCH + 128 + lane];
#pragma unroll
    for (int h = 0; h < 12; h++) {
        float a = 0.f;
#pragma unroll
        for (int g = 0; g < 12; g++) a += wt[h * 12 + g] * vr[g];
        out[token * EMBED + h * 64 + lane] = (__bf16)a;
    }
}

extern "C" void kernel_launch(void* const* d_in, const int* in_sizes, int n_in,
                              void* d_out, int out_size, void* d_ws, size_t ws_size,
                              hipStream_t stream) {
    const float* x     = (const float*)d_in[0];
    const float* w_qkv = (const float*)d_in[1];
    const float* b_qkv = (const float*)d_in[2];
    const float* w_o   = (const float*)d_in[3];
    const float* b_o   = (const float*)d_in[4];
    float* out = (float*)d_out;

    char* ws = (char*)d_ws;
    size_t off = 0;
    auto take = [&](size_t bytes) {
        char* p = ws + off;
        off += (bytes + 255) & ~(size_t)255;
        return p;
    };
    __bf16* wqkvp = (__bf16*)take((size_t)QKVN * KDIM * 2);   // packed B for GEMM1
    __bf16* wop   = (__bf16*)take((size_t)EMBED * KDIM * 2);  // packed B for GEMM2
    __bf16* xb    = (__bf16*)take((size_t)TOKENS * EMBED * 2);
    __bf16* qkvb  = (__bf16*)take((size_t)TOKENS * QKVN * 2);
    __bf16* attno = xb;  // x_bf16 dead after GEMM1; reuse

    int n4 = TOKENS * EMBED / 4;
    k_cvt_bf16<<<2048, 256, 0, stream>>>((const float4*)x, (bf16x4*)xb, n4);

    // pack weights into fragment order
    k_pack_b<<<(NKT * (QKVN / 16) * 2 * 64) / 256, 256, 0, stream>>>(w_qkv, wqkvp, QKVN);
    k_pack_b<<<(NKT * (EMBED / 16) * 2 * 64) / 256, 256, 0, stream>>>(w_o, wop, EMBED);

    // GEMM1: qkv = x @ w_qkv + b_qkv -> bf16   (2304 wg, %8==0)
    gemm_bl<__bf16><<<(TOKENS / 128) * (QKVN / 256), 256, 0, stream>>>(
        xb, wqkvp, b_qkv, qkvb, QKVN);

    k_attn<<<TOKENS / 4, 256, 0, stream>>>(qkvb, attno);

    // GEMM2: out = attn_out @ w_o + b_o -> f32  (768 wg, %8==0)
    gemm_bl<float><<<(TOKENS / 128) * (EMBED / 256), 256, 0, stream>>>(
        attno, wop, b_o, out, EMBED);
}